// Round 5
// baseline (1618.639 us; speedup 1.0000x reference)
//
#include <hip/hip_runtime.h>

// Problem: VOCAB=32000, H=1024, L=256, B=64.  Only batch row 0 matters
// (reference broadcasts hs[:, :1, :]), so this is a single-sequence GRU.
#define SENT 0xAAAAAAAAu

typedef float f32x4 __attribute__((ext_vector_type(4)));

__device__ __forceinline__ float sigf(float x) { return 1.0f / (1.0f + __expf(-x)); }
__device__ __forceinline__ float tanh_fast(float x) {
  float e = __expf(2.0f * x);
  return 1.0f - 2.0f / (e + 1.0f);
}

// ---------- K1 (v1): gi[t][j] = emb[x[t][0]] . w_ih[j] + b_ih[j] (+ b_hh[j] for j<2048) ----------
// grid 768 blocks (4 j-rows each) x 256 thr (thread = t). 3 blocks/CU for latency hiding.
// R1: LDS-staged variant was +78 us WORSE (emb rows are L2-resident; 12 waves/CU hide it).
__global__ __launch_bounds__(256) void k1_gi(const int* __restrict__ x,
                                             const float* __restrict__ emb,
                                             const float* __restrict__ w_ih,
                                             const float* __restrict__ b_ih,
                                             const float* __restrict__ b_hh,
                                             float* __restrict__ gi)
{
  const int j0 = blockIdx.x * 4;
  const int t  = threadIdx.x;
  const int idx = x[t * 64];                       // x[t][0]
  const float* er = emb + (size_t)idx * 1024;

  float acc[4];
#pragma unroll
  for (int j = 0; j < 4; ++j) {
    const int jj = j0 + j;
    acc[j] = b_ih[jj] + (jj < 2048 ? b_hh[jj] : 0.0f);  // fold b_hh for r,z gates
  }

  for (int kc = 0; kc < 1024; kc += 16) {
    const float4 e0 = *(const float4*)(er + kc);
    const float4 e1 = *(const float4*)(er + kc + 4);
    const float4 e2 = *(const float4*)(er + kc + 8);
    const float4 e3 = *(const float4*)(er + kc + 12);
    const float e[16] = {e0.x, e0.y, e0.z, e0.w, e1.x, e1.y, e1.z, e1.w,
                         e2.x, e2.y, e2.z, e2.w, e3.x, e3.y, e3.z, e3.w};
#pragma unroll
    for (int j = 0; j < 4; ++j) {
      const float* w = w_ih + (size_t)(j0 + j) * 1024 + kc;  // wave-uniform -> s_load
#pragma unroll
      for (int i = 0; i < 16; ++i) acc[j] = fmaf(e[i], w[i], acc[j]);
    }
  }
  *(float4*)(gi + (size_t)t * 3072 + j0) = make_float4(acc[0], acc[1], acc[2], acc[3]);
}

// ---------- K2 v5: barrier-free persistent recurrence ----------
// R2/R4 post-mortems: poll REQUEST COUNT is not the bottleneck (atomic->plain at
// same count: neutral; 4x fewer pollers: WORSE). R3: extra serialized RTs are fatal.
// Remaining chain at best (2.83us/step): detect + barrier1 + LDS round trip +
// compute + barrier2 — two block-wide syncs per step couple 8 waves' tails twice.
// v5 removes ALL intra-block coupling: 256 blocks x 256 thr = 1024 independent
// waves, one per h element. Each wave polls the WHOLE 4KB row of h[t-1] itself
// (lane owns 16 contiguous floats = 4 dwordx4 sc0 sc1, single vmcnt(0), reissue
// all if any of the 16 words is SENT). The successful poll IS the data read; no
// LDS, no __syncthreads anywhere in the loop. Step latency/wave = detection
// (~1-2 L3 RT, self-synchronized across waves by the data dependency) + ~300cy
// compute. Weights: 3 gate-rows x 16 contiguous columns = 48 f32/lane in VGPRs.
__global__ __launch_bounds__(256) void k2_rec(const float* __restrict__ w_hh,
                                              const float* __restrict__ b_hh,
                                              const float* __restrict__ gi,
                                              const float* __restrict__ w_out,
                                              unsigned int* __restrict__ hseq,
                                              float* __restrict__ acc)
{
  const int tid  = threadIdx.x;
  const int wv   = tid >> 6;                      // 0..3
  const int lane = tid & 63;
  const int hj   = __builtin_amdgcn_readfirstlane(blockIdx.x * 4 + wv);  // 0..1023

  // ---- weights: w[gate][c] = w_hh[(gate*1024+hj)*1024 + lane*16 + c*4 .. +3] ----
  f32x4 w[3][4];                                  // 48 f32/lane, coalesced load
#pragma unroll
  for (int gate = 0; gate < 3; ++gate) {
    const float* row = w_hh + (size_t)(gate * 1024 + hj) * 1024 + lane * 16;
#pragma unroll
    for (int c = 0; c < 4; ++c) w[gate][c] = *(const f32x4*)(row + c * 4);
  }
  const float bhh_n = b_hh[2048 + hj];
  float hp = 0.0f, wout_acc = 0.0f;

#pragma unroll 1
  for (int t = 0; t < 256; ++t) {
    // wave-uniform scalar prefetches (issue before the poll, overlap its RT)
    const float gi_r = gi[(size_t)t * 3072 + hj];
    const float gi_z = gi[(size_t)t * 3072 + 1024 + hj];
    const float gi_n = gi[(size_t)t * 3072 + 2048 + hj];
    const float wo   = w_out[(size_t)t * 1024 + hj];

    float ar = 0.f, az = 0.f, an = 0.f;

    if (t > 0) {
      // poll the full row t-1: lane owns h[lane*16 .. +15] (wave = 4KB coalesced)
      const float* p = (const float*)hseq + (size_t)(t - 1) * 1024 + lane * 16;
      f32x4 h0, h1, h2v, h3;
      for (;;) {
        asm volatile("global_load_dwordx4 %0, %4, off sc0 sc1\n\t"
                     "global_load_dwordx4 %1, %4, off offset:16 sc0 sc1\n\t"
                     "global_load_dwordx4 %2, %4, off offset:32 sc0 sc1\n\t"
                     "global_load_dwordx4 %3, %4, off offset:48 sc0 sc1\n\t"
                     "s_waitcnt vmcnt(0)"
                     : "=v"(h0), "=v"(h1), "=v"(h2v), "=v"(h3)
                     : "v"(p) : "memory");
        const bool ok =
            (__float_as_uint(h0.x) != SENT) & (__float_as_uint(h0.y) != SENT) &
            (__float_as_uint(h0.z) != SENT) & (__float_as_uint(h0.w) != SENT) &
            (__float_as_uint(h1.x) != SENT) & (__float_as_uint(h1.y) != SENT) &
            (__float_as_uint(h1.z) != SENT) & (__float_as_uint(h1.w) != SENT) &
            (__float_as_uint(h2v.x) != SENT) & (__float_as_uint(h2v.y) != SENT) &
            (__float_as_uint(h2v.z) != SENT) & (__float_as_uint(h2v.w) != SENT) &
            (__float_as_uint(h3.x) != SENT) & (__float_as_uint(h3.y) != SENT) &
            (__float_as_uint(h3.z) != SENT) & (__float_as_uint(h3.w) != SENT);
        if (__all(ok)) break;
      }
      // dots over this lane's 16 columns
      const f32x4 hc[4] = {h0, h1, h2v, h3};
#pragma unroll
      for (int c = 0; c < 4; ++c) {
        const f32x4 h4 = hc[c];
        const f32x4 wr = w[0][c], wz = w[1][c], wn = w[2][c];
        ar = fmaf(h4.x, wr.x, ar); ar = fmaf(h4.y, wr.y, ar);
        ar = fmaf(h4.z, wr.z, ar); ar = fmaf(h4.w, wr.w, ar);
        az = fmaf(h4.x, wz.x, az); az = fmaf(h4.y, wz.y, az);
        az = fmaf(h4.z, wz.z, az); az = fmaf(h4.w, wz.w, az);
        an = fmaf(h4.x, wn.x, an); an = fmaf(h4.y, wn.y, an);
        an = fmaf(h4.z, wn.z, an); an = fmaf(h4.w, wn.w, an);
      }
#pragma unroll
      for (int m = 1; m < 64; m <<= 1) {
        ar += __shfl_xor(ar, m, 64);
        az += __shfl_xor(az, m, 64);
        an += __shfl_xor(an, m, 64);
      }
    }

    const float r  = sigf(ar + gi_r);               // b_ih+b_hh folded into gi_r/gi_z
    const float z  = sigf(az + gi_z);
    const float n  = tanh_fast(gi_n + r * (an + bhh_n));
    const float h2 = (1.0f - z) * n + z * hp;

    unsigned int bits = __float_as_uint(h2);
    if (bits == SENT) bits ^= 1u;                   // never store the sentinel
    if (lane == 0) {
      // fire-and-forget store to the coherence point
      unsigned int* vp = hseq + (size_t)t * 1024 + hj;
      asm volatile("global_store_dword %0, %1, off sc0 sc1"
                   :: "v"(vp), "v"(bits) : "memory");
      wout_acc = fmaf(__uint_as_float(bits), wo, wout_acc);  // fold w_out dot in
    }
    hp = __uint_as_float(bits);
  }

  if (lane == 0) atomicAdd(acc, wout_acc);
}

// ---------- K3: pure feat broadcast: feat[b][i] = hseq[i] for all 64 b ----------
__global__ __launch_bounds__(256) void k3_bcast(const float* __restrict__ hseq_f,
                                                float* __restrict__ outbuf)
{
  const int gtid = blockIdx.x * 256 + threadIdx.x;
  const float4* src = (const float4*)hseq_f;    // 65536 float4
  float4* dst = (float4*)outbuf;
  for (int q = gtid; q < 64 * 65536; q += 1024 * 256) {
    const int b = q >> 16, i4 = q & 65535;
    dst[(size_t)b * 65536 + i4] = src[i4];
  }
}

// ---------- K4: out[b] = sigmoid(acc + b_out) for all 64 b ----------
__global__ void k4_fin(const float* __restrict__ acc, const float* __restrict__ b_out,
                       float* __restrict__ outbuf)
{
  const float s = sigf(acc[0] + b_out[0]);
  outbuf[(size_t)16777216 + threadIdx.x] = s;
}

// ---------- launch ----------
extern "C" void kernel_launch(void* const* d_in, const int* in_sizes, int n_in,
                              void* d_out, int out_size, void* d_ws, size_t ws_size,
                              hipStream_t stream) {
  const int*   x     = (const int*)d_in[0];
  const float* emb   = (const float*)d_in[1];
  const float* w_ih  = (const float*)d_in[2];
  const float* w_hh  = (const float*)d_in[3];
  const float* b_ih  = (const float*)d_in[4];
  const float* b_hh  = (const float*)d_in[5];
  const float* w_out = (const float*)d_in[6];
  const float* b_out = (const float*)d_in[7];
  float* out = (float*)d_out;

  char* ws = (char*)d_ws;
  float*        gi   = (float*)ws;                       // 3,145,728 B
  unsigned int* hseq = (unsigned int*)(ws + 3145728);    // 1,048,576 B
  float*        acc  = (float*)(ws + 4194304);           // 4 B

  hipMemsetAsync(hseq, 0xAA, (size_t)256 * 1024 * 4, stream);  // sentinel init
  hipMemsetAsync(acc, 0, 4, stream);

  hipLaunchKernelGGL(k1_gi,    dim3(768),  dim3(256), 0, stream, x, emb, w_ih, b_ih, b_hh, gi);
  hipLaunchKernelGGL(k2_rec,   dim3(256),  dim3(256), 0, stream, w_hh, b_hh, gi, w_out, hseq, acc);
  hipLaunchKernelGGL(k3_bcast, dim3(1024), dim3(256), 0, stream, (const float*)hseq, out);
  hipLaunchKernelGGL(k4_fin,   dim3(1),    dim3(64),  0, stream, acc, b_out, out);
}

// Round 6
// 795.502 us; speedup vs baseline: 2.0347x; 2.0347x over previous
//
#include <hip/hip_runtime.h>

// Problem: VOCAB=32000, H=1024, L=256, B=64.  Only batch row 0 matters
// (reference broadcasts hs[:, :1, :]), so this is a single-sequence GRU.
//
// R2-R5 established: the sentinel chunk-poll recurrence (128 blk x 8 waves,
// 2 barriers, ~725us) is a local optimum of the sync design space — flag-release
// (+2 RT): 1.7x worse; 4x fewer pollers w/ 4x compute: 1.26x worse; barrier-free
// full-row poll (65k line-req/round): 1.9x worse. k2's waves idle ~90%/step.
// R6: fuse K1 (gi GEMV, ~230-250us as a separate kernel) INTO the poll-wait idle
// time: wave hj computes its own 3 gi dots (48 FMA + 18 shfl + prefetched 4KB
// e-row) per step — ~200cy, hidden under the ~6000cy detection window.
#define SENT 0xAAAAAAAAu

typedef float f32x4 __attribute__((ext_vector_type(4)));

__device__ __forceinline__ float sigf(float x) { return 1.0f / (1.0f + __expf(-x)); }
__device__ __forceinline__ float tanh_fast(float x) {
  float e = __expf(2.0f * x);
  return 1.0f - 2.0f / (e + 1.0f);
}

// ---------- K2 v6: persistent recurrence with fused gi ----------
// grid 128 x 512 (8 waves). Wave wv of block g owns h element hj = 8g+wv.
// In VGPRs per lane: 3 w_hh row-chunks (48 f32) + 3 w_ih row-chunks (48 f32).
// Sync structure is the measured-725us R2 kernel, verbatim.
__global__ __launch_bounds__(512) void k2_rec(const int* __restrict__ x,
                                              const float* __restrict__ emb,
                                              const float* __restrict__ w_ih,
                                              const float* __restrict__ w_hh,
                                              const float* __restrict__ b_ih,
                                              const float* __restrict__ b_hh,
                                              const float* __restrict__ w_out,
                                              unsigned int* __restrict__ hseq,
                                              float* __restrict__ acc)
{
  __shared__ float hlds[1024];   // 4 KB

  const int g    = blockIdx.x;
  const int tid  = threadIdx.x;
  const int wv   = tid >> 6;
  const int lane = tid & 63;
  const int hj   = __builtin_amdgcn_readfirstlane(g * 8 + wv);  // uniform -> s_loads

  // ---- w_hh into VGPRs: w[gate*4+j] holds row[j*256 + lane*4 .. +3] ----
  f32x4 w[12];
#pragma unroll
  for (int gate = 0; gate < 3; ++gate) {
    const float* row = w_hh + (size_t)(gate * 1024 + hj) * 1024;
#pragma unroll
    for (int j = 0; j < 4; ++j)
      w[gate * 4 + j] = *(const f32x4*)(row + j * 256 + lane * 4);
  }
  // ---- w_ih into VGPRs: same k-split (k = c*256 + lane*4 + i) ----
  f32x4 wi[12];
#pragma unroll
  for (int gate = 0; gate < 3; ++gate) {
    const float* row = w_ih + (size_t)(gate * 1024 + hj) * 1024;
#pragma unroll
    for (int c = 0; c < 4; ++c)
      wi[gate * 4 + c] = *(const f32x4*)(row + c * 256 + lane * 4);
  }

  const float br  = b_ih[hj]        + b_hh[hj];          // fold b_hh for r,z
  const float bz  = b_ih[1024 + hj] + b_hh[1024 + hj];
  const float bni = b_ih[2048 + hj];
  const float bnh = b_hh[2048 + hj];

  float hp = 0.0f, wout_acc = 0.0f;
  const unsigned long long* hs64 = (const unsigned long long*)hseq;

  // ---- gi for t=0 (e-row 0, coalesced: k = c*256 + lane*4) ----
  f32x4 ep[4];
  {
    const float* er = emb + (size_t)x[0] * 1024;
#pragma unroll
    for (int c = 0; c < 4; ++c) ep[c] = *(const f32x4*)(er + c * 256 + lane * 4);
  }
  float gir, giz, gin;
  {
    float d0 = 0.f, d1 = 0.f, d2 = 0.f;
#pragma unroll
    for (int c = 0; c < 4; ++c) {
      const f32x4 e4 = ep[c];
      const f32x4 wr = wi[c], wz4 = wi[4 + c], wn4 = wi[8 + c];
      d0 = fmaf(e4.x, wr.x, d0); d0 = fmaf(e4.y, wr.y, d0);
      d0 = fmaf(e4.z, wr.z, d0); d0 = fmaf(e4.w, wr.w, d0);
      d1 = fmaf(e4.x, wz4.x, d1); d1 = fmaf(e4.y, wz4.y, d1);
      d1 = fmaf(e4.z, wz4.z, d1); d1 = fmaf(e4.w, wz4.w, d1);
      d2 = fmaf(e4.x, wn4.x, d2); d2 = fmaf(e4.y, wn4.y, d2);
      d2 = fmaf(e4.z, wn4.z, d2); d2 = fmaf(e4.w, wn4.w, d2);
    }
#pragma unroll
    for (int m = 1; m < 64; m <<= 1) {
      d0 += __shfl_xor(d0, m, 64);
      d1 += __shfl_xor(d1, m, 64);
      d2 += __shfl_xor(d2, m, 64);
    }
    gir = d0 + br; giz = d1 + bz; gin = d2 + bni;
  }
  // issue e-row prefetch for t=1
  {
    const float* er = emb + (size_t)x[64] * 1024;
#pragma unroll
    for (int c = 0; c < 4; ++c) ep[c] = *(const f32x4*)(er + c * 256 + lane * 4);
  }

#pragma unroll 1
  for (int t = 0; t < 256; ++t) {
    const float wo = w_out[(size_t)t * 1024 + hj];   // wave-uniform scalar prefetch

    float ar = 0.f, az = 0.f, an = 0.f;

    if (t > 0) {
      // poll own 512 B chunk of row t-1: one coalesced plain dwordx2 (sc0 sc1) per
      // lane per round; values are {SENT | final} so no atomicity needed, and a
      // successful poll IS the data read (detection overlapped with arrival).
      const unsigned long long* p = hs64 + (size_t)(t - 1) * 512 + wv * 64 + lane;
      unsigned long long v;
      for (;;) {
        asm volatile("global_load_dwordx2 %0, %1, off sc0 sc1\n\t"
                     "s_waitcnt vmcnt(0)"
                     : "=v"(v) : "v"(p) : "memory");
        const bool ok = (((unsigned int)v) != SENT) &
                        (((unsigned int)(v >> 32)) != SENT);
        if (__all(ok)) break;
      }
      const int w0 = wv * 128 + lane * 2;          // 8B-aligned -> ds_write_b64
      hlds[w0]     = __uint_as_float((unsigned int)v);
      hlds[w0 + 1] = __uint_as_float((unsigned int)(v >> 32));
      __syncthreads();                              // barrier1: hlds fully valid

      // dot: lane owns k = j*256 + lane*4 + c
#pragma unroll
      for (int j = 0; j < 4; ++j) {
        const f32x4 h4 = *(const f32x4*)&hlds[j * 256 + lane * 4];
        const f32x4 wr = w[j], wz4 = w[4 + j], wn4 = w[8 + j];
        ar = fmaf(h4.x, wr.x, ar); ar = fmaf(h4.y, wr.y, ar);
        ar = fmaf(h4.z, wr.z, ar); ar = fmaf(h4.w, wr.w, ar);
        az = fmaf(h4.x, wz4.x, az); az = fmaf(h4.y, wz4.y, az);
        az = fmaf(h4.z, wz4.z, az); az = fmaf(h4.w, wz4.w, az);
        an = fmaf(h4.x, wn4.x, an); an = fmaf(h4.y, wn4.y, an);
        an = fmaf(h4.z, wn4.z, an); an = fmaf(h4.w, wn4.w, an);
      }
#pragma unroll
      for (int m = 1; m < 64; m <<= 1) {
        ar += __shfl_xor(ar, m, 64);
        az += __shfl_xor(az, m, 64);
        an += __shfl_xor(an, m, 64);
      }
    }

    const float r  = sigf(ar + gir);
    const float z  = sigf(az + giz);
    const float n  = tanh_fast(gin + r * (an + bnh));
    const float h2 = (1.0f - z) * n + z * hp;

    unsigned int bits = __float_as_uint(h2);
    if (bits == SENT) bits ^= 1u;                   // never store the sentinel
    if (lane == 0) {
      // fire-and-forget store to the coherence point
      unsigned int* vp = hseq + (size_t)t * 1024 + hj;
      asm volatile("global_store_dword %0, %1, off sc0 sc1"
                   :: "v"(vp), "v"(bits) : "memory");
      wout_acc = fmaf(__uint_as_float(bits), wo, wout_acc);  // fold w_out dot in
    }
    hp = __uint_as_float(bits);

    // ---- fused gi for t+1 (hidden in the step's idle window) ----
    if (t < 255) {
      float d0 = 0.f, d1 = 0.f, d2 = 0.f;
#pragma unroll
      for (int c = 0; c < 4; ++c) {
        const f32x4 e4 = ep[c];
        const f32x4 wr = wi[c], wz4 = wi[4 + c], wn4 = wi[8 + c];
        d0 = fmaf(e4.x, wr.x, d0); d0 = fmaf(e4.y, wr.y, d0);
        d0 = fmaf(e4.z, wr.z, d0); d0 = fmaf(e4.w, wr.w, d0);
        d1 = fmaf(e4.x, wz4.x, d1); d1 = fmaf(e4.y, wz4.y, d1);
        d1 = fmaf(e4.z, wz4.z, d1); d1 = fmaf(e4.w, wz4.w, d1);
        d2 = fmaf(e4.x, wn4.x, d2); d2 = fmaf(e4.y, wn4.y, d2);
        d2 = fmaf(e4.z, wn4.z, d2); d2 = fmaf(e4.w, wn4.w, d2);
      }
#pragma unroll
      for (int m = 1; m < 64; m <<= 1) {
        d0 += __shfl_xor(d0, m, 64);
        d1 += __shfl_xor(d1, m, 64);
        d2 += __shfl_xor(d2, m, 64);
      }
      gir = d0 + br; giz = d1 + bz; gin = d2 + bni;
      if (t < 254) {                                // issue e-row for t+2
        const float* er = emb + (size_t)x[(t + 2) * 64] * 1024;
#pragma unroll
        for (int c = 0; c < 4; ++c) ep[c] = *(const f32x4*)(er + c * 256 + lane * 4);
      }
    }

    if (t > 0) __syncthreads();  // barrier2: hlds reads(t) done before fill(t+1)
  }

  if (lane == 0) atomicAdd(acc, wout_acc);
}

// ---------- K3: pure feat broadcast: feat[b][i] = hseq[i] for all 64 b ----------
__global__ __launch_bounds__(256) void k3_bcast(const float* __restrict__ hseq_f,
                                                float* __restrict__ outbuf)
{
  const int gtid = blockIdx.x * 256 + threadIdx.x;
  const float4* src = (const float4*)hseq_f;    // 65536 float4
  float4* dst = (float4*)outbuf;
  for (int q = gtid; q < 64 * 65536; q += 1024 * 256) {
    const int b = q >> 16, i4 = q & 65535;
    dst[(size_t)b * 65536 + i4] = src[i4];
  }
}

// ---------- K4: out[b] = sigmoid(acc + b_out) for all 64 b ----------
__global__ void k4_fin(const float* __restrict__ acc, const float* __restrict__ b_out,
                       float* __restrict__ outbuf)
{
  const float s = sigf(acc[0] + b_out[0]);
  outbuf[(size_t)16777216 + threadIdx.x] = s;
}

// ---------- launch ----------
extern "C" void kernel_launch(void* const* d_in, const int* in_sizes, int n_in,
                              void* d_out, int out_size, void* d_ws, size_t ws_size,
                              hipStream_t stream) {
  const int*   x     = (const int*)d_in[0];
  const float* emb   = (const float*)d_in[1];
  const float* w_ih  = (const float*)d_in[2];
  const float* w_hh  = (const float*)d_in[3];
  const float* b_ih  = (const float*)d_in[4];
  const float* b_hh  = (const float*)d_in[5];
  const float* w_out = (const float*)d_in[6];
  const float* b_out = (const float*)d_in[7];
  float* out = (float*)d_out;

  char* ws = (char*)d_ws;
  unsigned int* hseq = (unsigned int*)ws;                // 1,048,576 B
  float*        acc  = (float*)(ws + 1048576);           // 4 B

  hipMemsetAsync(hseq, 0xAA, (size_t)256 * 1024 * 4, stream);  // sentinel init
  hipMemsetAsync(acc, 0, 4, stream);

  hipLaunchKernelGGL(k2_rec,   dim3(128),  dim3(512), 0, stream,
                     x, emb, w_ih, w_hh, b_ih, b_hh, w_out, hseq, acc);
  hipLaunchKernelGGL(k3_bcast, dim3(1024), dim3(256), 0, stream, (const float*)hseq, out);
  hipLaunchKernelGGL(k4_fin,   dim3(1),    dim3(64),  0, stream, acc, b_out, out);
}